// Round 2
// baseline (361.035 us; speedup 1.0000x reference)
//
#include <hip/hip_runtime.h>

#define N_NODES 50000
#define N_EDGES 1600000
#define N_CAND  131072
#define D 128
#define ROWS 50176   // padded row count
#define NB 196       // coarse buckets (dst>>8)
#define BCAP 10240   // fixed per-bucket capacity (E[cnt]=8192, sigma~90)
#define LSTR 132     // LDS row stride (bf16 elems)
#define ZROW 50000   // zeroed row used as /dev/null for masked gather lanes

typedef __attribute__((ext_vector_type(8))) short short8;
typedef __attribute__((ext_vector_type(4))) float f32x4;

__device__ inline short f2bf(float f) {
  unsigned u = __builtin_bit_cast(unsigned, f);
  u = (u + 0x7FFFu + ((u >> 16) & 1u)) >> 16;
  return (short)u;
}
__device__ inline float bf_lo(unsigned u) { return __builtin_bit_cast(float, u << 16); }
__device__ inline float bf_hi(unsigned u) { return __builtin_bit_cast(float, u & 0xFFFF0000u); }
__device__ inline float bfu(unsigned short h) { return __builtin_bit_cast(float, (unsigned)h << 16); }

// ---------------- prep + pass1 merged (unchanged) ----------------

__global__ __launch_bounds__(256) void prep_pass1(const float* __restrict__ gw1,
                                                  const float* __restrict__ gw2,
                                                  const float* __restrict__ pw1,
                                                  short* __restrict__ Wf,
                                                  const float* __restrict__ x,
                                                  unsigned short* __restrict__ y,
                                                  const int* __restrict__ src,
                                                  const int* __restrict__ dst,
                                                  int* __restrict__ bucket_cnt,
                                                  int* __restrict__ pairs) {
  int b = blockIdx.x;
  int t = threadIdx.x;
  if (b < 64) {
    int tid = b * 256 + t;  // 0..16383
    int img = tid >> 11, idx = tid & 2047;
    const float* W;
    if (img < 3) W = gw1 + img * 16384;
    else if (img < 6) W = gw2 + (img - 3) * 16384;
    else W = pw1 + (256 + (img - 6) * 128) * 128;
    int n = idx & 127, k8 = idx >> 7;
    short8 s;
#pragma unroll
    for (int j = 0; j < 8; ++j) s[j] = f2bf(W[(k8 * 8 + j) * 128 + n]);
    int kk = k8 >> 2, q = k8 & 3, nt = n >> 4, ln = (n & 15) | (q << 4);
    *(short8*)&Wf[img * 16384 + ((nt * 4 + kk) * 64 + ln) * 8] = s;
  } else if (b < 3189) {
    size_t base = ((size_t)(b - 64) * 256 + t) * 8;
    float4 v0 = *(const float4*)&x[base];
    float4 v1 = *(const float4*)&x[base + 4];
    short8 s;
    s[0] = f2bf(v0.x); s[1] = f2bf(v0.y); s[2] = f2bf(v0.z); s[3] = f2bf(v0.w);
    s[4] = f2bf(v1.x); s[5] = f2bf(v1.y); s[6] = f2bf(v1.z); s[7] = f2bf(v1.w);
    *(short8*)&y[base] = s;
  } else {
    __shared__ int lcnt[NB];
    __shared__ int loff[NB];
    __shared__ int gbase[NB];
    __shared__ int scanbuf[256];
    __shared__ int stage[4096];
    int e0 = (b - 3189) * 4096;
    for (int i = t; i < NB; i += 256) lcnt[i] = 0;
    __syncthreads();
    int d[16], s[16], r[16];
#pragma unroll
    for (int i = 0; i < 16; ++i) {
      int e = e0 + i * 256 + t;
      if (e < N_EDGES) {
        d[i] = dst[e]; s[i] = src[e];
        r[i] = atomicAdd(&lcnt[d[i] >> 8], 1);
      } else d[i] = -1;
    }
    __syncthreads();
    {
      int v = (t < NB) ? lcnt[t] : 0;
      scanbuf[t] = v;
      __syncthreads();
      for (int off = 1; off < 256; off <<= 1) {
        int add = (t >= off) ? scanbuf[t - off] : 0;
        __syncthreads();
        scanbuf[t] += add;
        __syncthreads();
      }
      if (t < NB) {
        loff[t] = scanbuf[t] - v;
        gbase[t] = v ? atomicAdd(&bucket_cnt[t], v) : 0;
      }
    }
    __syncthreads();
#pragma unroll
    for (int i = 0; i < 16; ++i) {
      if (d[i] >= 0) {
        int bb = d[i] >> 8;
        stage[loff[bb] + r[i]] = (s[i] << 8) | (d[i] & 255);
      }
    }
    __syncthreads();
    int w = t >> 6, lane = t & 63;
    for (int bb = w; bb < NB; bb += 4) {
      int c = lcnt[bb], lo = loff[bb], gb = bb * BCAP + gbase[bb];
      for (int k = lane; k < c; k += 64) pairs[gb + k] = stage[lo + k];
    }
  }
}

// ---------------- pass2: within-bucket counting sort (unchanged) ----------------

__global__ __launch_bounds__(512) void build_pass2(const int* __restrict__ pairs,
                                                   const int* __restrict__ bucket_cnt,
                                                   int2* __restrict__ rowBE,
                                                   int* __restrict__ csr) {
  __shared__ int cnt_s[256];
  __shared__ int buf[256];
  __shared__ int ssrc[BCAP];
  int t = threadIdx.x;
  int b = blockIdx.x;
  int cnt = bucket_cnt[b];
  int gbase = b * BCAP;
  const int* pp = pairs + gbase;
  if (t < 256) cnt_s[t] = 0;
  __syncthreads();
  for (int i = t; i < cnt; i += 512) atomicAdd(&cnt_s[pp[i] & 255], 1);
  __syncthreads();
  int v = 0;
  if (t < 256) { v = cnt_s[t]; buf[t] = v; }
  __syncthreads();
  for (int off = 1; off < 256; off <<= 1) {
    int add = (t >= off && t < 256) ? buf[t - off] : 0;
    __syncthreads();
    if (t < 256) buf[t] += add;
    __syncthreads();
  }
  if (t < 256) {
    int excl = buf[t] - v;
    int node = (b << 8) + t;
    if (node < N_NODES) rowBE[node] = make_int2(gbase + excl, gbase + excl + v);
    cnt_s[t] = excl;
  }
  __syncthreads();
  for (int i = t; i < cnt; i += 512) {
    int p = pp[i];
    int pos = atomicAdd(&cnt_s[p & 255], 1);
    ssrc[pos] = p >> 8;
  }
  __syncthreads();
  for (int i = t; i < cnt; i += 512) csr[gbase + i] = ssrc[i];
}

// ---------------- fused GIN layer v2: 4-parallel-node gather (16-lane groups,
// dwordx4 row loads, ds_bpermute src broadcast) + 16-row MFMA MLP ----------------

__global__ __launch_bounds__(256, 6) void gin_layer(const unsigned short* __restrict__ xin,
                                                    const int2* __restrict__ rowBE,
                                                    const int* __restrict__ csr,
                                                    const short* __restrict__ B1f,
                                                    const float* __restrict__ b1,
                                                    const short* __restrict__ B2f,
                                                    const float* __restrict__ b2,
                                                    unsigned short* __restrict__ xout) {
  __shared__ short hbuf[16 * LSTR];   // 4224 B
  int t = threadIdx.x;
  int w = t >> 6, lane = t & 63;
  int g = lane >> 4, m = lane & 15;     // 16-lane group g handles one node
  int node0 = blockIdx.x * 16;          // grid 3125: exact cover of 50000
  int node = node0 + w * 4 + g;
  const char* xb = (const char*)xin;
  const char* xrow = xb + m * 16;       // each lane owns 16B (8 bf16) of a row

  int2 be = rowBE[node];
  int beg = be.x, cnt = be.y - be.x;

  // init accumulator with own row: h = x + agg
  float a[8];
  {
    uint4 v = *(const uint4*)(xb + ((size_t)node << 8) + m * 16);
    a[0] = bf_lo(v.x); a[1] = bf_hi(v.x);
    a[2] = bf_lo(v.y); a[3] = bf_hi(v.y);
    a[4] = bf_lo(v.z); a[5] = bf_hi(v.z);
    a[6] = bf_lo(v.w); a[7] = bf_hi(v.w);
  }

  // wave-uniform max degree over the 4 groups
  int mc = cnt;
  mc = max(mc, __shfl_xor(mc, 16));
  mc = max(mc, __shfl_xor(mc, 32));
  int maxcnt = __builtin_amdgcn_readfirstlane(mc);

  int baddr = (lane & 48) << 2;         // bpermute byte base of this group
  int zoff = ZROW << 8;                 // masked lanes read the zeroed row

  for (int base = 0; base < maxcnt; base += 64) {
    int sidx[4];
#pragma unroll
    for (int k = 0; k < 4; ++k)
      sidx[k] = csr[beg + base + k * 16 + m];   // may over-read within bucket: masked below
#pragma unroll
    for (int k = 0; k < 4; ++k) {
#pragma unroll
      for (int h2 = 0; h2 < 2; ++h2) {
        int e0 = base + k * 16 + h2 * 8;
        if (e0 < maxcnt) {              // wave-uniform branch
          uint4 v[8];
#pragma unroll
          for (int j = 0; j < 8; ++j) {
            int srcv = __builtin_amdgcn_ds_bpermute(baddr | ((h2 * 8 + j) << 2), sidx[k]);
            int roff = (e0 + j < cnt) ? (srcv << 8) : zoff;
            v[j] = *(const uint4*)(xrow + roff);
          }
#pragma unroll
          for (int j = 0; j < 8; ++j) {
            a[0] += bf_lo(v[j].x); a[1] += bf_hi(v[j].x);
            a[2] += bf_lo(v[j].y); a[3] += bf_hi(v[j].y);
            a[4] += bf_lo(v[j].z); a[5] += bf_hi(v[j].z);
            a[6] += bf_lo(v[j].w); a[7] += bf_hi(v[j].w);
          }
        }
      }
    }
  }

  // write h row into LDS (2-way bank aliasing only = free)
  {
    int row = w * 4 + g;
#pragma unroll
    for (int jj = 0; jj < 4; ++jj) {
      unsigned p = (unsigned)(unsigned short)f2bf(a[2 * jj]) |
                   ((unsigned)(unsigned short)f2bf(a[2 * jj + 1]) << 16);
      *(unsigned*)&hbuf[row * LSTR + m * 8 + 2 * jj] = p;
    }
  }
  __syncthreads();

  // ---- MLP (unchanged structure): layer 1 ----
  short8 a0f[4];
#pragma unroll
  for (int kk = 0; kk < 4; ++kk)
    a0f[kk] = *(short8*)&hbuf[m * LSTR + kk * 32 + g * 8];
  __syncthreads();

  f32x4 acc[2] = {};
#pragma unroll
  for (int kk = 0; kk < 4; ++kk)
#pragma unroll
    for (int j = 0; j < 2; ++j) {
      int nt = w * 2 + j;
      short8 bf = *(const short8*)&B1f[((nt * 4 + kk) * 64 + lane) * 8];
      acc[j] = __builtin_amdgcn_mfma_f32_16x16x32_bf16(a0f[kk], bf, acc[j], 0, 0, 0);
    }
#pragma unroll
  for (int j = 0; j < 2; ++j) {
    int nt = w * 2 + j;
    float bv = b1[nt * 16 + m];
#pragma unroll
    for (int r = 0; r < 4; ++r)
      hbuf[(g * 4 + r) * LSTR + nt * 16 + m] = f2bf(fmaxf(acc[j][r] + bv, 0.f));
  }
  __syncthreads();

  // ---- layer 2 ----
  short8 a1f[4];
#pragma unroll
  for (int kk = 0; kk < 4; ++kk)
    a1f[kk] = *(short8*)&hbuf[m * LSTR + kk * 32 + g * 8];
  __syncthreads();

  f32x4 acc2[2] = {};
#pragma unroll
  for (int kk = 0; kk < 4; ++kk)
#pragma unroll
    for (int j = 0; j < 2; ++j) {
      int nt = w * 2 + j;
      short8 bf = *(const short8*)&B2f[((nt * 4 + kk) * 64 + lane) * 8];
      acc2[j] = __builtin_amdgcn_mfma_f32_16x16x32_bf16(a1f[kk], bf, acc2[j], 0, 0, 0);
    }
#pragma unroll
  for (int j = 0; j < 2; ++j) {
    int nt = w * 2 + j;
    float bv = b2[nt * 16 + m];
#pragma unroll
    for (int r = 0; r < 4; ++r)
      hbuf[(g * 4 + r) * LSTR + nt * 16 + m] = f2bf(acc2[j][r] + bv);
  }
  __syncthreads();

  {
    int row = t >> 4, c8 = t & 15;
    short8 vv = *(short8*)&hbuf[row * LSTR + c8 * 8];
    *(short8*)&xout[(size_t)(node0 + row) * D + c8 * 8] = vv;
  }
}

// ---------------- predictor: explicit 16-deep prefetch staging (unchanged) ----------------

__global__ __launch_bounds__(256, 4) void pred_kernel(const unsigned short* __restrict__ x,
                                                      const int* __restrict__ cand,
                                                      const short* __restrict__ Wf,
                                                      const int* __restrict__ ep,
                                                      const float* __restrict__ W1,
                                                      const float* __restrict__ b1,
                                                      const float* __restrict__ w2,
                                                      const float* __restrict__ b2,
                                                      float* __restrict__ out) {
  __shared__ short sS[16384];
  __shared__ short sD[16384];
  __shared__ float su[128], sv[128];
  __shared__ float partb[2][128];
  __shared__ float tvec_s[128];
  int t = threadIdx.x;
  int blockRow = blockIdx.x * 128;
  int w = t >> 6, lane = t & 63;

  if (t < 128) {
    int u = ep[0], vv = ep[1];
    su[t] = bfu(x[(size_t)u * D + t]);
    sv[t] = bfu(x[(size_t)vv * D + t]);
  }

  short8 U[8], V[8];
#pragma unroll
  for (int i = 0; i < 8; ++i) {
    int idx = t + i * 256;
    int c = blockRow + (idx >> 4);
    int2 uv = ((const int2*)cand)[c];
    int j8 = idx & 15;
    U[i] = *(const short8*)&x[(size_t)uv.x * D + j8 * 8];
    V[i] = *(const short8*)&x[(size_t)uv.y * D + j8 * 8];
  }
#pragma unroll
  for (int i = 0; i < 8; ++i) {
    int idx = t + i * 256;
    int m = idx >> 4, j8 = idx & 15;
    short8 ss, sd;
#pragma unroll
    for (int j = 0; j < 8; ++j) {
      float uf = bfu((unsigned short)U[i][j]);
      float vf = bfu((unsigned short)V[i][j]);
      ss[j] = f2bf(uf + vf);
      sd[j] = f2bf(fabsf(uf - vf));
    }
    int kk = j8 >> 2, qq = j8 & 3, mt = m >> 4, ln = (m & 15) | (qq << 4);
    int slot = ((mt * 4 + kk) * 64 + ln) * 8;
    *(short8*)&sS[slot] = ss;
    *(short8*)&sD[slot] = sd;
  }
  __syncthreads();

  {
    int j = t & 127, seg = t >> 7;
    const float* Wp = W1 + seg * 128 * D;
    float acc = 0.f;
#pragma unroll 8
    for (int k = 0; k < 128; ++k) {
      float f = seg ? fabsf(su[k] - sv[k]) : (su[k] + sv[k]);
      acc += f * Wp[k * D + j];
    }
    partb[seg][j] = acc;
  }
  __syncthreads();
  if (t < 128) tvec_s[t] = b1[t] + partb[0][t] + partb[1][t];
  __syncthreads();

  f32x4 acc[2][8] = {};
  const short* B0 = Wf + 6 * 16384;
  const short* B1 = Wf + 7 * 16384;
  for (int kk = 0; kk < 4; ++kk) {
    short8 a0[2], a1[2];
#pragma unroll
    for (int mt = 0; mt < 2; ++mt) {
      a0[mt] = *(short8*)&sS[(((w * 2 + mt) * 4 + kk) * 64 + lane) * 8];
      a1[mt] = *(short8*)&sD[(((w * 2 + mt) * 4 + kk) * 64 + lane) * 8];
    }
#pragma unroll
    for (int nt = 0; nt < 8; ++nt) {
      short8 b0 = *(const short8*)&B0[((nt * 4 + kk) * 64 + lane) * 8];
      short8 b1f = *(const short8*)&B1[((nt * 4 + kk) * 64 + lane) * 8];
#pragma unroll
      for (int mt = 0; mt < 2; ++mt) {
        acc[mt][nt] = __builtin_amdgcn_mfma_f32_16x16x32_bf16(a0[mt], b0, acc[mt][nt], 0, 0, 0);
        acc[mt][nt] = __builtin_amdgcn_mfma_f32_16x16x32_bf16(a1[mt], b1f, acc[mt][nt], 0, 0, 0);
      }
    }
  }

  int colbase = lane & 15, rq = lane >> 4;
  float tv[8], w2v[8];
#pragma unroll
  for (int nt = 0; nt < 8; ++nt) {
    tv[nt] = tvec_s[nt * 16 + colbase];
    w2v[nt] = w2[nt * 16 + colbase];
  }
  float b2v = b2[0];
#pragma unroll
  for (int mt = 0; mt < 2; ++mt) {
    float part[4] = {0.f, 0.f, 0.f, 0.f};
#pragma unroll
    for (int nt = 0; nt < 8; ++nt)
#pragma unroll
      for (int r = 0; r < 4; ++r) {
        float h = acc[mt][nt][r] + tv[nt];
        h = fmaxf(h, 0.f);
        part[r] += h * w2v[nt];
      }
#pragma unroll
    for (int r = 0; r < 4; ++r)
      for (int msk = 1; msk < 16; msk <<= 1)
        part[r] += __shfl_xor(part[r], msk, 64);
    if (colbase == 0) {
      int row0 = blockRow + (w * 2 + mt) * 16 + rq * 4;
#pragma unroll
      for (int r = 0; r < 4; ++r) out[row0 + r] = part[r] + b2v;
    }
  }
}

// ---------------- launch ----------------

extern "C" void kernel_launch(void* const* d_in, const int* in_sizes, int n_in,
                              void* d_out, int out_size, void* d_ws, size_t ws_size,
                              hipStream_t stream) {
  const float* x_in = (const float*)d_in[0];
  const int* edge_index = (const int*)d_in[1];
  const int* ep = (const int*)d_in[2];
  const int* cand = (const int*)d_in[3];
  const float* gw1 = (const float*)d_in[4];
  const float* gb1 = (const float*)d_in[5];
  const float* gw2 = (const float*)d_in[6];
  const float* gb2 = (const float*)d_in[7];
  const float* pw1 = (const float*)d_in[8];
  const float* pb1 = (const float*)d_in[9];
  const float* pw2 = (const float*)d_in[10];
  const float* pb2 = (const float*)d_in[11];
  float* out = (float*)d_out;

  char* ws = (char*)d_ws;
  size_t off = 0;
  auto alloc = [&](size_t bytes) {
    void* p = ws + off;
    off += (bytes + 255) & ~(size_t)255;
    return p;
  };
  unsigned short* xA = (unsigned short*)alloc((size_t)ROWS * D * 2);
  unsigned short* xB = (unsigned short*)alloc((size_t)ROWS * D * 2);
  int* pairs       = (int*)alloc((size_t)NB * BCAP * 4);
  int* csr         = (int*)alloc((size_t)NB * BCAP * 4);
  int2* rowBE      = (int2*)alloc((size_t)N_NODES * 8);
  int* bucket_cnt  = (int*)alloc((size_t)NB * 4);
  short* Wf        = (short*)alloc((size_t)8 * 16384 * 2);

  const int* src = edge_index;
  const int* dst = edge_index + N_EDGES;

  hipMemsetAsync(bucket_cnt, 0, (size_t)NB * 4, stream);
  // zero the /dev/null row used by masked gather lanes (both ping-pong buffers)
  hipMemsetAsync(xA + (size_t)ZROW * D, 0, (size_t)D * 2, stream);
  hipMemsetAsync(xB + (size_t)ZROW * D, 0, (size_t)D * 2, stream);

  prep_pass1<<<3580, 256, 0, stream>>>(gw1, gw2, pw1, Wf, x_in, xA, src, dst, bucket_cnt, pairs);
  build_pass2<<<NB, 512, 0, stream>>>(pairs, bucket_cnt, rowBE, csr);

  const int gin_grid = N_NODES / 16;  // 3125
  gin_layer<<<gin_grid, 256, 0, stream>>>(xA, rowBE, csr, Wf + 0 * 16384, gb1 + 0 * D,
                                          Wf + 3 * 16384, gb2 + 0 * D, xB);
  gin_layer<<<gin_grid, 256, 0, stream>>>(xB, rowBE, csr, Wf + 1 * 16384, gb1 + 1 * D,
                                          Wf + 4 * 16384, gb2 + 1 * D, xA);
  gin_layer<<<gin_grid, 256, 0, stream>>>(xA, rowBE, csr, Wf + 2 * 16384, gb1 + 2 * D,
                                          Wf + 5 * 16384, gb2 + 2 * D, xB);

  pred_kernel<<<N_CAND / 128, 256, 0, stream>>>(xB, cand, Wf, ep, pw1, pb1, pw2, pb2, out);
}

// Round 3
// 335.085 us; speedup vs baseline: 1.0774x; 1.0774x over previous
//
#include <hip/hip_runtime.h>

#define N_NODES 50000
#define N_EDGES 1600000
#define N_CAND  131072
#define D 128
#define ROWS 50176   // padded row count
#define NB 196       // coarse buckets (dst>>8)
#define BCAP 10240   // fixed per-bucket capacity (E[cnt]=8192, sigma~90)
#define LSTR 132     // LDS row stride (bf16 elems)

typedef __attribute__((ext_vector_type(8))) short short8;
typedef __attribute__((ext_vector_type(4))) float f32x4;

__device__ inline short f2bf(float f) {
  unsigned u = __builtin_bit_cast(unsigned, f);
  u = (u + 0x7FFFu + ((u >> 16) & 1u)) >> 16;
  return (short)u;
}
__device__ inline float bf_lo(unsigned u) { return __builtin_bit_cast(float, u << 16); }
__device__ inline float bf_hi(unsigned u) { return __builtin_bit_cast(float, u & 0xFFFF0000u); }
__device__ inline float bfu(unsigned short h) { return __builtin_bit_cast(float, (unsigned)h << 16); }

// ---------------- prep + pass1 merged (unchanged) ----------------

__global__ __launch_bounds__(256) void prep_pass1(const float* __restrict__ gw1,
                                                  const float* __restrict__ gw2,
                                                  const float* __restrict__ pw1,
                                                  short* __restrict__ Wf,
                                                  const float* __restrict__ x,
                                                  unsigned short* __restrict__ y,
                                                  const int* __restrict__ src,
                                                  const int* __restrict__ dst,
                                                  int* __restrict__ bucket_cnt,
                                                  int* __restrict__ pairs) {
  int b = blockIdx.x;
  int t = threadIdx.x;
  if (b < 64) {
    int tid = b * 256 + t;  // 0..16383
    int img = tid >> 11, idx = tid & 2047;
    const float* W;
    if (img < 3) W = gw1 + img * 16384;
    else if (img < 6) W = gw2 + (img - 3) * 16384;
    else W = pw1 + (256 + (img - 6) * 128) * 128;
    int n = idx & 127, k8 = idx >> 7;
    short8 s;
#pragma unroll
    for (int j = 0; j < 8; ++j) s[j] = f2bf(W[(k8 * 8 + j) * 128 + n]);
    int kk = k8 >> 2, q = k8 & 3, nt = n >> 4, ln = (n & 15) | (q << 4);
    *(short8*)&Wf[img * 16384 + ((nt * 4 + kk) * 64 + ln) * 8] = s;
  } else if (b < 3189) {
    size_t base = ((size_t)(b - 64) * 256 + t) * 8;
    float4 v0 = *(const float4*)&x[base];
    float4 v1 = *(const float4*)&x[base + 4];
    short8 s;
    s[0] = f2bf(v0.x); s[1] = f2bf(v0.y); s[2] = f2bf(v0.z); s[3] = f2bf(v0.w);
    s[4] = f2bf(v1.x); s[5] = f2bf(v1.y); s[6] = f2bf(v1.z); s[7] = f2bf(v1.w);
    *(short8*)&y[base] = s;
  } else {
    __shared__ int lcnt[NB];
    __shared__ int loff[NB];
    __shared__ int gbase[NB];
    __shared__ int scanbuf[256];
    __shared__ int stage[4096];
    int e0 = (b - 3189) * 4096;
    for (int i = t; i < NB; i += 256) lcnt[i] = 0;
    __syncthreads();
    int d[16], s[16], r[16];
#pragma unroll
    for (int i = 0; i < 16; ++i) {
      int e = e0 + i * 256 + t;
      if (e < N_EDGES) {
        d[i] = dst[e]; s[i] = src[e];
        r[i] = atomicAdd(&lcnt[d[i] >> 8], 1);
      } else d[i] = -1;
    }
    __syncthreads();
    {
      int v = (t < NB) ? lcnt[t] : 0;
      scanbuf[t] = v;
      __syncthreads();
      for (int off = 1; off < 256; off <<= 1) {
        int add = (t >= off) ? scanbuf[t - off] : 0;
        __syncthreads();
        scanbuf[t] += add;
        __syncthreads();
      }
      if (t < NB) {
        loff[t] = scanbuf[t] - v;
        gbase[t] = v ? atomicAdd(&bucket_cnt[t], v) : 0;
      }
    }
    __syncthreads();
#pragma unroll
    for (int i = 0; i < 16; ++i) {
      if (d[i] >= 0) {
        int bb = d[i] >> 8;
        stage[loff[bb] + r[i]] = (s[i] << 8) | (d[i] & 255);
      }
    }
    __syncthreads();
    int w = t >> 6, lane = t & 63;
    for (int bb = w; bb < NB; bb += 4) {
      int c = lcnt[bb], lo = loff[bb], gb = bb * BCAP + gbase[bb];
      for (int k = lane; k < c; k += 64) pairs[gb + k] = stage[lo + k];
    }
  }
}

// ---------------- pass2: within-bucket counting sort (unchanged) ----------------

__global__ __launch_bounds__(512) void build_pass2(const int* __restrict__ pairs,
                                                   const int* __restrict__ bucket_cnt,
                                                   int2* __restrict__ rowBE,
                                                   int* __restrict__ csr) {
  __shared__ int cnt_s[256];
  __shared__ int buf[256];
  __shared__ int ssrc[BCAP];
  int t = threadIdx.x;
  int b = blockIdx.x;
  int cnt = bucket_cnt[b];
  int gbase = b * BCAP;
  const int* pp = pairs + gbase;
  if (t < 256) cnt_s[t] = 0;
  __syncthreads();
  for (int i = t; i < cnt; i += 512) atomicAdd(&cnt_s[pp[i] & 255], 1);
  __syncthreads();
  int v = 0;
  if (t < 256) { v = cnt_s[t]; buf[t] = v; }
  __syncthreads();
  for (int off = 1; off < 256; off <<= 1) {
    int add = (t >= off && t < 256) ? buf[t - off] : 0;
    __syncthreads();
    if (t < 256) buf[t] += add;
    __syncthreads();
  }
  if (t < 256) {
    int excl = buf[t] - v;
    int node = (b << 8) + t;
    if (node < N_NODES) rowBE[node] = make_int2(gbase + excl, gbase + excl + v);
    cnt_s[t] = excl;
  }
  __syncthreads();
  for (int i = t; i < cnt; i += 512) {
    int p = pp[i];
    int pos = atomicAdd(&cnt_s[p & 255], 1);
    ssrc[pos] = p >> 8;
  }
  __syncthreads();
  for (int i = t; i < cnt; i += 512) csr[gbase + i] = ssrc[i];
}

// ---------------- fused GIN layer v3: v1 structure (whole-row readlane gather)
// with __launch_bounds__(256,4) so the 32-deep batch ladder can actually
// allocate its in-flight registers (v1 compiled to VGPR=32 -> serialized) ----------------

__global__ __launch_bounds__(256, 4) void gin_layer(const unsigned short* __restrict__ xin,
                                                    const int2* __restrict__ rowBE,
                                                    const int* __restrict__ csr,
                                                    const short* __restrict__ B1f,
                                                    const float* __restrict__ b1,
                                                    const short* __restrict__ B2f,
                                                    const float* __restrict__ b2,
                                                    unsigned short* __restrict__ xout) {
  __shared__ short hbuf[16 * LSTR];   // 4224 B
  int t = threadIdx.x;
  int w = t >> 6, lane = t & 63;
  int node0 = blockIdx.x * 16;        // grid 3125: exact cover of 50000
  const char* xb = (const char*)xin;
  int voff = lane * 4;

  for (int i = 0; i < 4; ++i) {
    int node = node0 + w * 4 + i;
    int2 be = rowBE[node];
    int beg = be.x, end = be.y;
    unsigned sv = *(const unsigned*)(xb + (size_t)node * 256 + voff);
    float a0 = bf_lo(sv), a1 = bf_hi(sv);
    for (int e = beg; e < end; e += 64) {
      int cnt = min(64, end - e);
      int sidx = (e + lane < end) ? csr[e + lane] : 0;
      int ii = 0;
      for (; ii + 32 <= cnt; ii += 32) {
        unsigned v[32];
#pragma unroll
        for (int j = 0; j < 32; ++j) {
          int s = __builtin_amdgcn_readlane(sidx, ii + j);   // SGPR index
          v[j] = *(const unsigned*)(xb + ((size_t)(unsigned)s << 8) + voff);
        }
#pragma unroll
        for (int j = 0; j < 32; ++j) { a0 += bf_lo(v[j]); a1 += bf_hi(v[j]); }
      }
      for (; ii + 16 <= cnt; ii += 16) {
        unsigned v[16];
#pragma unroll
        for (int j = 0; j < 16; ++j) {
          int s = __builtin_amdgcn_readlane(sidx, ii + j);
          v[j] = *(const unsigned*)(xb + ((size_t)(unsigned)s << 8) + voff);
        }
#pragma unroll
        for (int j = 0; j < 16; ++j) { a0 += bf_lo(v[j]); a1 += bf_hi(v[j]); }
      }
      for (; ii + 8 <= cnt; ii += 8) {
        unsigned v[8];
#pragma unroll
        for (int j = 0; j < 8; ++j) {
          int s = __builtin_amdgcn_readlane(sidx, ii + j);
          v[j] = *(const unsigned*)(xb + ((size_t)(unsigned)s << 8) + voff);
        }
#pragma unroll
        for (int j = 0; j < 8; ++j) { a0 += bf_lo(v[j]); a1 += bf_hi(v[j]); }
      }
      for (; ii < cnt; ++ii) {
        int s = __builtin_amdgcn_readlane(sidx, ii);
        unsigned v = *(const unsigned*)(xb + ((size_t)(unsigned)s << 8) + voff);
        a0 += bf_lo(v); a1 += bf_hi(v);
      }
    }
    unsigned r = (unsigned)(unsigned short)f2bf(a0) | ((unsigned)(unsigned short)f2bf(a1) << 16);
    *(unsigned*)&hbuf[(w * 4 + i) * LSTR + lane * 2] = r;
  }
  __syncthreads();

  int q = lane >> 4, m = lane & 15;
  short8 a0f[4];
#pragma unroll
  for (int kk = 0; kk < 4; ++kk)
    a0f[kk] = *(short8*)&hbuf[m * LSTR + kk * 32 + q * 8];
  __syncthreads();

  f32x4 acc[2] = {};
#pragma unroll
  for (int kk = 0; kk < 4; ++kk)
#pragma unroll
    for (int j = 0; j < 2; ++j) {
      int nt = w * 2 + j;
      short8 bf = *(const short8*)&B1f[((nt * 4 + kk) * 64 + lane) * 8];
      acc[j] = __builtin_amdgcn_mfma_f32_16x16x32_bf16(a0f[kk], bf, acc[j], 0, 0, 0);
    }
#pragma unroll
  for (int j = 0; j < 2; ++j) {
    int nt = w * 2 + j;
    float bv = b1[nt * 16 + m];
#pragma unroll
    for (int r = 0; r < 4; ++r)
      hbuf[(q * 4 + r) * LSTR + nt * 16 + m] = f2bf(fmaxf(acc[j][r] + bv, 0.f));
  }
  __syncthreads();

  short8 a1f[4];
#pragma unroll
  for (int kk = 0; kk < 4; ++kk)
    a1f[kk] = *(short8*)&hbuf[m * LSTR + kk * 32 + q * 8];
  __syncthreads();

  f32x4 acc2[2] = {};
#pragma unroll
  for (int kk = 0; kk < 4; ++kk)
#pragma unroll
    for (int j = 0; j < 2; ++j) {
      int nt = w * 2 + j;
      short8 bf = *(const short8*)&B2f[((nt * 4 + kk) * 64 + lane) * 8];
      acc2[j] = __builtin_amdgcn_mfma_f32_16x16x32_bf16(a1f[kk], bf, acc2[j], 0, 0, 0);
    }
#pragma unroll
  for (int j = 0; j < 2; ++j) {
    int nt = w * 2 + j;
    float bv = b2[nt * 16 + m];
#pragma unroll
    for (int r = 0; r < 4; ++r)
      hbuf[(q * 4 + r) * LSTR + nt * 16 + m] = f2bf(acc2[j][r] + bv);
  }
  __syncthreads();

  {
    int row = t >> 4, c8 = t & 15;
    short8 vv = *(short8*)&hbuf[row * LSTR + c8 * 8];
    *(short8*)&xout[(size_t)(node0 + row) * D + c8 * 8] = vv;
  }
}

// ---------------- predictor: explicit 16-deep prefetch staging (unchanged) ----------------

__global__ __launch_bounds__(256, 4) void pred_kernel(const unsigned short* __restrict__ x,
                                                      const int* __restrict__ cand,
                                                      const short* __restrict__ Wf,
                                                      const int* __restrict__ ep,
                                                      const float* __restrict__ W1,
                                                      const float* __restrict__ b1,
                                                      const float* __restrict__ w2,
                                                      const float* __restrict__ b2,
                                                      float* __restrict__ out) {
  __shared__ short sS[16384];
  __shared__ short sD[16384];
  __shared__ float su[128], sv[128];
  __shared__ float partb[2][128];
  __shared__ float tvec_s[128];
  int t = threadIdx.x;
  int blockRow = blockIdx.x * 128;
  int w = t >> 6, lane = t & 63;

  if (t < 128) {
    int u = ep[0], vv = ep[1];
    su[t] = bfu(x[(size_t)u * D + t]);
    sv[t] = bfu(x[(size_t)vv * D + t]);
  }

  short8 U[8], V[8];
#pragma unroll
  for (int i = 0; i < 8; ++i) {
    int idx = t + i * 256;
    int c = blockRow + (idx >> 4);
    int2 uv = ((const int2*)cand)[c];
    int j8 = idx & 15;
    U[i] = *(const short8*)&x[(size_t)uv.x * D + j8 * 8];
    V[i] = *(const short8*)&x[(size_t)uv.y * D + j8 * 8];
  }
#pragma unroll
  for (int i = 0; i < 8; ++i) {
    int idx = t + i * 256;
    int m = idx >> 4, j8 = idx & 15;
    short8 ss, sd;
#pragma unroll
    for (int j = 0; j < 8; ++j) {
      float uf = bfu((unsigned short)U[i][j]);
      float vf = bfu((unsigned short)V[i][j]);
      ss[j] = f2bf(uf + vf);
      sd[j] = f2bf(fabsf(uf - vf));
    }
    int kk = j8 >> 2, qq = j8 & 3, mt = m >> 4, ln = (m & 15) | (qq << 4);
    int slot = ((mt * 4 + kk) * 64 + ln) * 8;
    *(short8*)&sS[slot] = ss;
    *(short8*)&sD[slot] = sd;
  }
  __syncthreads();

  {
    int j = t & 127, seg = t >> 7;
    const float* Wp = W1 + seg * 128 * D;
    float acc = 0.f;
#pragma unroll 8
    for (int k = 0; k < 128; ++k) {
      float f = seg ? fabsf(su[k] - sv[k]) : (su[k] + sv[k]);
      acc += f * Wp[k * D + j];
    }
    partb[seg][j] = acc;
  }
  __syncthreads();
  if (t < 128) tvec_s[t] = b1[t] + partb[0][t] + partb[1][t];
  __syncthreads();

  f32x4 acc[2][8] = {};
  const short* B0 = Wf + 6 * 16384;
  const short* B1 = Wf + 7 * 16384;
  for (int kk = 0; kk < 4; ++kk) {
    short8 a0[2], a1[2];
#pragma unroll
    for (int mt = 0; mt < 2; ++mt) {
      a0[mt] = *(short8*)&sS[(((w * 2 + mt) * 4 + kk) * 64 + lane) * 8];
      a1[mt] = *(short8*)&sD[(((w * 2 + mt) * 4 + kk) * 64 + lane) * 8];
    }
#pragma unroll
    for (int nt = 0; nt < 8; ++nt) {
      short8 b0 = *(const short8*)&B0[((nt * 4 + kk) * 64 + lane) * 8];
      short8 b1f = *(const short8*)&B1[((nt * 4 + kk) * 64 + lane) * 8];
#pragma unroll
      for (int mt = 0; mt < 2; ++mt) {
        acc[mt][nt] = __builtin_amdgcn_mfma_f32_16x16x32_bf16(a0[mt], b0, acc[mt][nt], 0, 0, 0);
        acc[mt][nt] = __builtin_amdgcn_mfma_f32_16x16x32_bf16(a1[mt], b1f, acc[mt][nt], 0, 0, 0);
      }
    }
  }

  int colbase = lane & 15, rq = lane >> 4;
  float tv[8], w2v[8];
#pragma unroll
  for (int nt = 0; nt < 8; ++nt) {
    tv[nt] = tvec_s[nt * 16 + colbase];
    w2v[nt] = w2[nt * 16 + colbase];
  }
  float b2v = b2[0];
#pragma unroll
  for (int mt = 0; mt < 2; ++mt) {
    float part[4] = {0.f, 0.f, 0.f, 0.f};
#pragma unroll
    for (int nt = 0; nt < 8; ++nt)
#pragma unroll
      for (int r = 0; r < 4; ++r) {
        float h = acc[mt][nt][r] + tv[nt];
        h = fmaxf(h, 0.f);
        part[r] += h * w2v[nt];
      }
#pragma unroll
    for (int r = 0; r < 4; ++r)
      for (int msk = 1; msk < 16; msk <<= 1)
        part[r] += __shfl_xor(part[r], msk, 64);
    if (colbase == 0) {
      int row0 = blockRow + (w * 2 + mt) * 16 + rq * 4;
#pragma unroll
      for (int r = 0; r < 4; ++r) out[row0 + r] = part[r] + b2v;
    }
  }
}

// ---------------- launch ----------------

extern "C" void kernel_launch(void* const* d_in, const int* in_sizes, int n_in,
                              void* d_out, int out_size, void* d_ws, size_t ws_size,
                              hipStream_t stream) {
  const float* x_in = (const float*)d_in[0];
  const int* edge_index = (const int*)d_in[1];
  const int* ep = (const int*)d_in[2];
  const int* cand = (const int*)d_in[3];
  const float* gw1 = (const float*)d_in[4];
  const float* gb1 = (const float*)d_in[5];
  const float* gw2 = (const float*)d_in[6];
  const float* gb2 = (const float*)d_in[7];
  const float* pw1 = (const float*)d_in[8];
  const float* pb1 = (const float*)d_in[9];
  const float* pw2 = (const float*)d_in[10];
  const float* pb2 = (const float*)d_in[11];
  float* out = (float*)d_out;

  char* ws = (char*)d_ws;
  size_t off = 0;
  auto alloc = [&](size_t bytes) {
    void* p = ws + off;
    off += (bytes + 255) & ~(size_t)255;
    return p;
  };
  unsigned short* xA = (unsigned short*)alloc((size_t)ROWS * D * 2);
  unsigned short* xB = (unsigned short*)alloc((size_t)ROWS * D * 2);
  int* pairs       = (int*)alloc((size_t)NB * BCAP * 4);
  int* csr         = (int*)alloc((size_t)NB * BCAP * 4);
  int2* rowBE      = (int2*)alloc((size_t)N_NODES * 8);
  int* bucket_cnt  = (int*)alloc((size_t)NB * 4);
  short* Wf        = (short*)alloc((size_t)8 * 16384 * 2);

  const int* src = edge_index;
  const int* dst = edge_index + N_EDGES;

  hipMemsetAsync(bucket_cnt, 0, (size_t)NB * 4, stream);
  prep_pass1<<<3580, 256, 0, stream>>>(gw1, gw2, pw1, Wf, x_in, xA, src, dst, bucket_cnt, pairs);
  build_pass2<<<NB, 512, 0, stream>>>(pairs, bucket_cnt, rowBE, csr);

  const int gin_grid = N_NODES / 16;  // 3125
  gin_layer<<<gin_grid, 256, 0, stream>>>(xA, rowBE, csr, Wf + 0 * 16384, gb1 + 0 * D,
                                          Wf + 3 * 16384, gb2 + 0 * D, xB);
  gin_layer<<<gin_grid, 256, 0, stream>>>(xB, rowBE, csr, Wf + 1 * 16384, gb1 + 1 * D,
                                          Wf + 4 * 16384, gb2 + 1 * D, xA);
  gin_layer<<<gin_grid, 256, 0, stream>>>(xA, rowBE, csr, Wf + 2 * 16384, gb1 + 2 * D,
                                          Wf + 5 * 16384, gb2 + 2 * D, xB);

  pred_kernel<<<N_CAND / 128, 256, 0, stream>>>(xB, cand, Wf, ep, pw1, pb1, pw2, pb2, out);
}